// Round 14
// baseline (456.080 us; speedup 1.0000x reference)
//
#include <hip/hip_runtime.h>

#define B_ 256
#define T_ 512
#define F_ 64
#define U_ 128

typedef _Float16 h2v __attribute__((ext_vector_type(2)));
union U32H2 { unsigned u; h2v h; };

__device__ __forceinline__ float fdot2(unsigned a, unsigned b, float c) {
  U32H2 x, y; x.u = a; y.u = b;
  return __builtin_amdgcn_fdot2(x.h, y.h, c, false);
}
__device__ __forceinline__ unsigned packh2(float a, float b) {
  U32H2 r; r.h[0] = (_Float16)a; r.h[1] = (_Float16)b; return r.u;
}
// sum over each aligned group of 8 lanes (kg = lane&7); all 8 lanes get the total.
__device__ __forceinline__ float red8(float v) {
  int t = __builtin_amdgcn_update_dpp(0, __float_as_int(v), 0xB1, 0xF, 0xF, true);  // xor1
  v += __int_as_float(t);
  t = __builtin_amdgcn_update_dpp(0, __float_as_int(v), 0x4E, 0xF, 0xF, true);      // xor2
  v += __int_as_float(t);
  t = __builtin_amdgcn_update_dpp(0, __float_as_int(v), 0x141, 0xF, 0xF, true);     // xor4
  v += __int_as_float(t);
  return v;
}
__device__ __forceinline__ float fast_sig(float x) {
  return __builtin_amdgcn_rcpf(1.0f + __expf(-x));
}
__device__ __forceinline__ float fast_tanh(float x) {
  return fmaf(-2.0f, __builtin_amdgcn_rcpf(1.0f + __expf(2.0f * x)), 1.0f);
}

#define D4(acc, Hv, Wr, o)                                        \
  acc = fdot2(Hv.x, Wr[(o)], acc);                                \
  acc = fdot2(Hv.y, Wr[(o) + 1], acc);                            \
  acc = fdot2(Hv.z, Wr[(o) + 2], acc);                            \
  acc = fdot2(Hv.w, Wr[(o) + 3], acc);

__global__ __launch_bounds__(512)
__attribute__((amdgpu_waves_per_eu(2, 2)))
void grud_kernel(
    const float* __restrict__ x, const float* __restrict__ m,
    const float* __restrict__ delta_t,
    const float* __restrict__ Wz_, const float* __restrict__ Uz, const float* __restrict__ bz,
    const float* __restrict__ Wr_, const float* __restrict__ Ur, const float* __restrict__ br,
    const float* __restrict__ Wh_, const float* __restrict__ Uh, const float* __restrict__ bh,
    const float* __restrict__ gxd, const float* __restrict__ ghd,
    const float* __restrict__ mi,
    float* __restrict__ out)
{
  const int tid = threadIdx.x;
  const int b   = blockIdx.x;
  const int kg  = tid & 7;     // k-group: k in [16kg, 16kg+16); f in [8kg, 8kg+8)
  const int cp  = tid >> 3;    // column pair: cols {2cp, 2cp+1}
  const int c0  = 2 * cp;
  const bool wr_lane = (kg == 0);

  __shared__ float  s_dt[520];
  __shared__ float  s_ghv[32 * U_];               // per-chunk decay factors
  __shared__ float  s_hist[32 * U_];              // per-chunk outputs (fp32)
  __shared__ __align__(16) ushort s_x16[32 * F_]; // per-chunk decayed x (fp16)
  __shared__ __align__(16) ushort s_hd16[U_];
  __shared__ __align__(16) ushort s_rh16[U_];
  __shared__ float  s_negg[U_];
  __shared__ float  s_gxf[F_];
  __shared__ float  s_mi[F_];

  // ---- weights into registers: 72 packed fp16-pair words ----
  unsigned uz[16], ur[16], uh[16];   // [0..8)=col0, [8..16)=col1
  unsigned wz[8],  wr[8],  wh[8];    // [0..4)=col0, [4..8)=col1
#pragma unroll
  for (int j = 0; j < 8; ++j) {
    const int k0 = 16 * kg + 2 * j;
    uz[j]     = packh2(Uz[k0 * U_ + c0],     Uz[(k0 + 1) * U_ + c0]);
    uz[8 + j] = packh2(Uz[k0 * U_ + c0 + 1], Uz[(k0 + 1) * U_ + c0 + 1]);
    ur[j]     = packh2(Ur[k0 * U_ + c0],     Ur[(k0 + 1) * U_ + c0]);
    ur[8 + j] = packh2(Ur[k0 * U_ + c0 + 1], Ur[(k0 + 1) * U_ + c0 + 1]);
    uh[j]     = packh2(Uh[k0 * U_ + c0],     Uh[(k0 + 1) * U_ + c0]);
    uh[8 + j] = packh2(Uh[k0 * U_ + c0 + 1], Uh[(k0 + 1) * U_ + c0 + 1]);
  }
#pragma unroll
  for (int j = 0; j < 4; ++j) {
    const int f0 = 8 * kg + 2 * j;
    wz[j]     = packh2(Wz_[f0 * U_ + c0],     Wz_[(f0 + 1) * U_ + c0]);
    wz[4 + j] = packh2(Wz_[f0 * U_ + c0 + 1], Wz_[(f0 + 1) * U_ + c0 + 1]);
    wr[j]     = packh2(Wr_[f0 * U_ + c0],     Wr_[(f0 + 1) * U_ + c0]);
    wr[4 + j] = packh2(Wr_[f0 * U_ + c0 + 1], Wr_[(f0 + 1) * U_ + c0 + 1]);
    wh[j]     = packh2(Wh_[f0 * U_ + c0],     Wh_[(f0 + 1) * U_ + c0]);
    wh[4 + j] = packh2(Wh_[f0 * U_ + c0 + 1], Wh_[(f0 + 1) * U_ + c0 + 1]);
  }
  const float bz0 = bz[c0], bz1 = bz[c0 + 1];
  const float br0 = br[c0], br1 = br[c0 + 1];
  const float bh0 = bh[c0], bh1 = bh[c0 + 1];

  // ---- one-time LDS tables ----
  {
    const float* dtb = delta_t + (size_t)b * T_;
    if (tid < 512) s_dt[tid] = dtb[tid];
    if (tid < 8)   s_dt[512 + tid] = 0.0f;
    if (tid < U_)  { s_negg[tid] = -fmaxf(ghd[tid], 0.0f); ((unsigned*)s_hd16)[tid >> 1] = 0u; }
    if (tid < F_)  { s_gxf[tid] = -fmaxf(gxd[tid], 0.0f); s_mi[tid] = mi[tid]; }
  }
  __syncthreads();

  float hd0 = 0.0f, hd1 = 0.0f;                       // own columns' h_dec (fp32)
  float axz0 = 0.f, axz1 = 0.f, axr0 = 0.f, axr1 = 0.f, axh0 = 0.f, axh1 = 0.f;

  for (int t0 = 0; t0 < T_; t0 += 32) {
    // ======== chunk staging (bulk; only place with global loads) ========
    {
      const int e4 = tid;                      // 0..511 quad-groups of [32][64]
      const int t = e4 >> 4, f0 = (e4 & 15) << 2;
      const float dtv = s_dt[t0 + t];
      const float4 xv  = *(const float4*)(x + (size_t)(b * T_ + t0 + t) * F_ + f0);
      const float4 mv  = *(const float4*)(m + (size_t)(b * T_ + t0 + t) * F_ + f0);
      const float4 gv  = *(const float4*)(s_gxf + f0);
      const float4 miv = *(const float4*)(s_mi + f0);
      float gx, d0, d1, d2, d3;
      gx = __expf(gv.x * dtv);
      d0 = fmaf(mv.x, xv.x, (1.0f - mv.x) * (gx * xv.x + (1.0f - gx) * miv.x));
      gx = __expf(gv.y * dtv);
      d1 = fmaf(mv.y, xv.y, (1.0f - mv.y) * (gx * xv.y + (1.0f - gx) * miv.y));
      gx = __expf(gv.z * dtv);
      d2 = fmaf(mv.z, xv.z, (1.0f - mv.z) * (gx * xv.z + (1.0f - gx) * miv.z));
      gx = __expf(gv.w * dtv);
      d3 = fmaf(mv.w, xv.w, (1.0f - mv.w) * (gx * xv.w + (1.0f - gx) * miv.w));
      uint2 px; px.x = packh2(d0, d1); px.y = packh2(d2, d3);
      *(uint2*)(s_x16 + 4 * e4) = px;
    }
    // decay table for this chunk: ghv[t][c] = exp(-g_c * dt[t0+t+1])
#pragma unroll
    for (int i = 0; i < 8; ++i) {
      const int e = tid + 512 * i;             // 0..4095
      const int t = e >> 7, cc = e & 127;
      s_ghv[e] = __expf(s_negg[cc] * s_dt[t0 + t + 1]);
    }
    __syncthreads();

    // chunk prologue: x-projections for tc = 0 (both columns, all 3 gates)
    {
      const uint4 Xv = *(const uint4*)(s_x16 + 8 * kg);
      float a0 = 0.f, a1 = 0.f, a2 = 0.f, a3 = 0.f, a4 = 0.f, a5 = 0.f;
      D4(a0, Xv, wz, 0)  D4(a1, Xv, wz, 4)
      D4(a2, Xv, wr, 0)  D4(a3, Xv, wr, 4)
      D4(a4, Xv, wh, 0)  D4(a5, Xv, wh, 4)
      axz0 = a0; axz1 = a1; axr0 = a2; axr1 = a3; axh0 = a4; axh1 = a5;
    }

    // ======== 32 recurrent steps: LDS-only ========
#pragma unroll 1
    for (int tc = 0; tc < 32; ++tc) {
      // ---- window B: z, r (shared h reads, reused for both columns) ----
      const uint4* hp = (const uint4*)(s_hd16 + 16 * kg);
      const uint4 H0 = hp[0], H1 = hp[1];
      float az0 = axz0, az1 = axz1, ar0 = axr0, ar1 = axr1;
      D4(ar0, H0, ur, 0)  D4(ar1, H0, ur, 8)
      D4(ar0, H1, ur, 4)  D4(ar1, H1, ur, 12)
      D4(az0, H0, uz, 0)  D4(az1, H0, uz, 8)
      D4(az0, H1, uz, 4)  D4(az1, H1, uz, 12)
      const float r0 = fast_sig(red8(ar0) + br0);
      const float r1 = fast_sig(red8(ar1) + br1);
      if (wr_lane) ((unsigned*)s_rh16)[cp] = packh2(r0 * hd0, r1 * hd1);
      const float z0 = fast_sig(red8(az0) + bz0);
      const float z1 = fast_sig(red8(az1) + bz1);
      // filler: next-step z x-projection (independent)
      if (tc < 31) {
        const uint4 Xv = *(const uint4*)(s_x16 + (tc + 1) * F_ + 8 * kg);
        float a0 = 0.f, a1 = 0.f;
        D4(a0, Xv, wz, 0)  D4(a1, Xv, wz, 4)
        axz0 = a0; axz1 = a1;
      }
      __syncthreads();

      // ---- window C: candidate + update ----
      const float2 ghv = ((const float2*)s_ghv)[tc * 64 + cp];
      const uint4* rp = (const uint4*)(s_rh16 + 16 * kg);
      const uint4 R0 = rp[0], R1 = rp[1];
      float ah0 = axh0, ah1 = axh1;
      D4(ah0, R0, uh, 0)  D4(ah1, R0, uh, 8)
      D4(ah0, R1, uh, 4)  D4(ah1, R1, uh, 12)
      const float hh0 = fast_tanh(red8(ah0) + bh0);
      const float hh1 = fast_tanh(red8(ah1) + bh1);
      const float hn0 = fmaf(z0, hh0 - hd0, hd0);
      const float hn1 = fmaf(z1, hh1 - hd1, hd1);
      hd0 = ghv.x * hn0;
      hd1 = ghv.y * hn1;
      if (wr_lane) ((unsigned*)s_hd16)[cp] = packh2(hd0, hd1);  // unblock ASAP
      // filler: next-step r/h x-projections, then hist write
      if (tc < 31) {
        const uint4 Xv = *(const uint4*)(s_x16 + (tc + 1) * F_ + 8 * kg);
        float a2 = 0.f, a3 = 0.f, a4 = 0.f, a5 = 0.f;
        D4(a2, Xv, wr, 0)  D4(a3, Xv, wr, 4)
        D4(a4, Xv, wh, 0)  D4(a5, Xv, wh, 4)
        axr0 = a2; axr1 = a3; axh0 = a4; axh1 = a5;
      }
      if (wr_lane) ((float2*)s_hist)[tc * 64 + cp] = make_float2(hn0, hn1);
      __syncthreads();
    }

    // ======== flush chunk outputs (coalesced) ========
    {
      const float4* h4 = (const float4*)s_hist;
      float4* o4 = (float4*)(out + (size_t)(b * T_ + t0) * U_);
#pragma unroll
      for (int i = 0; i < 2; ++i) o4[tid + 512 * i] = h4[tid + 512 * i];
    }
  }
}

extern "C" void kernel_launch(void* const* d_in, const int* in_sizes, int n_in,
                              void* d_out, int out_size, void* d_ws, size_t ws_size,
                              hipStream_t stream) {
  const float* x   = (const float*)d_in[0];
  const float* m   = (const float*)d_in[1];
  const float* dt  = (const float*)d_in[2];
  const float* Wz  = (const float*)d_in[3];
  const float* Uz  = (const float*)d_in[4];
  const float* bz  = (const float*)d_in[5];
  const float* Wr  = (const float*)d_in[6];
  const float* Ur  = (const float*)d_in[7];
  const float* br  = (const float*)d_in[8];
  const float* Wh  = (const float*)d_in[9];
  const float* Uh  = (const float*)d_in[10];
  const float* bh  = (const float*)d_in[11];
  const float* gxd = (const float*)d_in[12];
  const float* ghd = (const float*)d_in[13];
  const float* mi  = (const float*)d_in[14];

  grud_kernel<<<dim3(B_), dim3(512), 0, stream>>>(
      x, m, dt, Wz, Uz, bz, Wr, Ur, br, Wh, Uh, bh, gxd, ghd, mi, (float*)d_out);
}

// Round 15
// 328.077 us; speedup vs baseline: 1.3902x; 1.3902x over previous
//
#include <hip/hip_runtime.h>

#define B_ 256
#define T_ 512
#define F_ 64
#define U_ 128
#define LOG2E 1.4426950408889634f
#define TSC   2.8853900817779268f   // 2*log2(e), folds the tanh 2x

typedef _Float16 h2v __attribute__((ext_vector_type(2)));
union U32H2 { unsigned u; h2v h; };

__device__ __forceinline__ float fdot2(unsigned a, unsigned b, float c) {
  U32H2 x, y; x.u = a; y.u = b;
  return __builtin_amdgcn_fdot2(x.h, y.h, c, false);
}
__device__ __forceinline__ unsigned packh2(float a, float b) {
  U32H2 r; r.h[0] = (_Float16)a; r.h[1] = (_Float16)b; return r.u;
}
__device__ __forceinline__ float dpp1(float v) {  // quad_perm [1,0,3,2]
  return __int_as_float(__builtin_amdgcn_update_dpp(0, __float_as_int(v), 0xB1, 0xF, 0xF, true));
}
__device__ __forceinline__ float dpp2(float v) {  // quad_perm [2,3,0,1]
  return __int_as_float(__builtin_amdgcn_update_dpp(0, __float_as_int(v), 0x4E, 0xF, 0xF, true));
}

#define D4(acc, Hv, Wr, o)                                        \
  acc = fdot2(Hv.x, Wr[(o)], acc);                                \
  acc = fdot2(Hv.y, Wr[(o) + 1], acc);                            \
  acc = fdot2(Hv.z, Wr[(o) + 2], acc);                            \
  acc = fdot2(Hv.w, Wr[(o) + 3], acc);

__global__ __launch_bounds__(256, 1)
__attribute__((amdgpu_waves_per_eu(1, 1)))
void grud_kernel(
    const float* __restrict__ x, const float* __restrict__ m,
    const float* __restrict__ delta_t,
    const float* __restrict__ Wz_, const float* __restrict__ Uz, const float* __restrict__ bz,
    const float* __restrict__ Wr_, const float* __restrict__ Ur, const float* __restrict__ br,
    const float* __restrict__ Wh_, const float* __restrict__ Uh, const float* __restrict__ bh,
    const float* __restrict__ gxd, const float* __restrict__ ghd,
    const float* __restrict__ mi,
    float* __restrict__ out)
{
  const int tid = threadIdx.x;
  const int b   = blockIdx.x;
  const int kg  = tid & 3;     // k-group: k in [32kg, 32kg+32); f in [16kg, 16kg+16)
  const int cp  = tid >> 2;    // column pair: cols {2cp, 2cp+1}
  const int c0  = 2 * cp;

  __shared__ float  s_dt[520];
  __shared__ float  s_ghv[32 * U_];               // per-chunk decay factors
  __shared__ float  s_hist[32 * U_];              // per-chunk outputs (fp32)
  __shared__ __align__(16) ushort s_x16[32 * F_]; // per-chunk decayed x (fp16)
  __shared__ __align__(16) ushort s_hd16[U_];
  __shared__ __align__(16) ushort s_rh16[U_];
  __shared__ float  s_negg[U_];
  __shared__ float  s_gxf[F_];
  __shared__ float  s_mi[F_];

  // ---- weights into registers, PRESCALED: z/r by log2e, h by 2*log2e ----
  unsigned uz[32], ur[32], uh[32];   // [0..16)=col0, [16..32)=col1
  unsigned wz[16], wr[16], wh[16];   // [0..8)=col0, [8..16)=col1
#pragma unroll
  for (int j = 0; j < 16; ++j) {
    const int k0 = 32 * kg + 2 * j;
    uz[j]      = packh2(LOG2E * Uz[k0 * U_ + c0],     LOG2E * Uz[(k0 + 1) * U_ + c0]);
    uz[16 + j] = packh2(LOG2E * Uz[k0 * U_ + c0 + 1], LOG2E * Uz[(k0 + 1) * U_ + c0 + 1]);
    ur[j]      = packh2(LOG2E * Ur[k0 * U_ + c0],     LOG2E * Ur[(k0 + 1) * U_ + c0]);
    ur[16 + j] = packh2(LOG2E * Ur[k0 * U_ + c0 + 1], LOG2E * Ur[(k0 + 1) * U_ + c0 + 1]);
    uh[j]      = packh2(TSC * Uh[k0 * U_ + c0],       TSC * Uh[(k0 + 1) * U_ + c0]);
    uh[16 + j] = packh2(TSC * Uh[k0 * U_ + c0 + 1],   TSC * Uh[(k0 + 1) * U_ + c0 + 1]);
  }
#pragma unroll
  for (int j = 0; j < 8; ++j) {
    const int f0 = 16 * kg + 2 * j;
    wz[j]     = packh2(LOG2E * Wz_[f0 * U_ + c0],     LOG2E * Wz_[(f0 + 1) * U_ + c0]);
    wz[8 + j] = packh2(LOG2E * Wz_[f0 * U_ + c0 + 1], LOG2E * Wz_[(f0 + 1) * U_ + c0 + 1]);
    wr[j]     = packh2(LOG2E * Wr_[f0 * U_ + c0],     LOG2E * Wr_[(f0 + 1) * U_ + c0]);
    wr[8 + j] = packh2(LOG2E * Wr_[f0 * U_ + c0 + 1], LOG2E * Wr_[(f0 + 1) * U_ + c0 + 1]);
    wh[j]     = packh2(TSC * Wh_[f0 * U_ + c0],       TSC * Wh_[(f0 + 1) * U_ + c0]);
    wh[8 + j] = packh2(TSC * Wh_[f0 * U_ + c0 + 1],   TSC * Wh_[(f0 + 1) * U_ + c0 + 1]);
  }
  // per-lane gate bias: kg0->r(col0), kg1->r(col1), kg2->z(col0), kg3->z(col1)
  const float biasB = (kg == 0) ? LOG2E * br[c0]
                    : (kg == 1) ? LOG2E * br[c0 + 1]
                    : (kg == 2) ? LOG2E * bz[c0]
                                : LOG2E * bz[c0 + 1];
  const float biasC = (kg & 1) ? TSC * bh[c0 + 1] : TSC * bh[c0];

  // ---- one-time LDS tables ----
  {
    const float* dtb = delta_t + (size_t)b * T_;
    s_dt[tid]       = dtb[tid];
    s_dt[tid + 256] = dtb[tid + 256];
    if (tid < 8)   s_dt[512 + tid] = 0.0f;
    if (tid < U_)  { s_negg[tid] = -fmaxf(ghd[tid], 0.0f); ((unsigned*)s_hd16)[tid >> 1] = 0u; }
    if (tid < F_)  { s_gxf[tid] = -fmaxf(gxd[tid], 0.0f); s_mi[tid] = mi[tid]; }
  }
  __syncthreads();

  float hdk = 0.0f;   // per-lane hidden-state: kg0 holds hd[c0], kg1 holds hd[c0+1]
  float axz0 = 0.f, axz1 = 0.f, axr0 = 0.f, axr1 = 0.f, axh0 = 0.f, axh1 = 0.f;

  for (int t0 = 0; t0 < T_; t0 += 32) {
    // ======== chunk staging (bulk; only place with global loads) ========
#pragma unroll
    for (int i = 0; i < 2; ++i) {
      const int e4 = tid + 256 * i;            // 0..511 quad-groups
      const int t = e4 >> 4, f0 = (e4 & 15) << 2;
      const float dtv = s_dt[t0 + t];
      const float4 xv  = *(const float4*)(x + (size_t)(b * T_ + t0 + t) * F_ + f0);
      const float4 mv  = *(const float4*)(m + (size_t)(b * T_ + t0 + t) * F_ + f0);
      const float4 gv  = *(const float4*)(s_gxf + f0);
      const float4 miv = *(const float4*)(s_mi + f0);
      float gx, d0, d1, d2, d3;
      gx = __expf(gv.x * dtv);
      d0 = fmaf(mv.x, xv.x, (1.0f - mv.x) * (gx * xv.x + (1.0f - gx) * miv.x));
      gx = __expf(gv.y * dtv);
      d1 = fmaf(mv.y, xv.y, (1.0f - mv.y) * (gx * xv.y + (1.0f - gx) * miv.y));
      gx = __expf(gv.z * dtv);
      d2 = fmaf(mv.z, xv.z, (1.0f - mv.z) * (gx * xv.z + (1.0f - gx) * miv.z));
      gx = __expf(gv.w * dtv);
      d3 = fmaf(mv.w, xv.w, (1.0f - mv.w) * (gx * xv.w + (1.0f - gx) * miv.w));
      uint2 px; px.x = packh2(d0, d1); px.y = packh2(d2, d3);
      *(uint2*)(s_x16 + 4 * e4) = px;
    }
    // decay table for this chunk: ghv[t][c] = exp(-g_c * dt[t0+t+1])
#pragma unroll
    for (int i = 0; i < 16; ++i) {
      const int e = tid + 256 * i;             // 0..4095
      const int t = e >> 7, cc = e & 127;
      s_ghv[e] = __expf(s_negg[cc] * s_dt[t0 + t + 1]);
    }
    __syncthreads();

    // chunk prologue: x-projections for tc = 0 (both columns, all 3 gates)
    {
      const uint4* xp = (const uint4*)(s_x16 + 16 * kg);
      float a0 = 0.f, a1 = 0.f, a2 = 0.f, a3 = 0.f, a4 = 0.f, a5 = 0.f;
#pragma unroll
      for (int q = 0; q < 2; ++q) {
        const uint4 Xv = xp[q];
        D4(a0, Xv, wz, 4 * q)  D4(a1, Xv, wz, 8 + 4 * q)
        D4(a2, Xv, wr, 4 * q)  D4(a3, Xv, wr, 8 + 4 * q)
        D4(a4, Xv, wh, 4 * q)  D4(a5, Xv, wh, 8 + 4 * q)
      }
      axz0 = a0; axz1 = a1; axr0 = a2; axr1 = a3; axh0 = a4; axh1 = a5;
    }

    // ======== 32 recurrent steps: LDS-only ========
#pragma unroll 1
    for (int tc = 0; tc < 32; ++tc) {
      // ---- window B: z, r (shared h reads, reused for both columns) ----
      const uint4* hp = (const uint4*)(s_hd16 + 32 * kg);
      float az0 = axz0, az1 = axz1, ar0 = axr0, ar1 = axr1;
#pragma unroll
      for (int j = 0; j < 4; ++j) {
        const uint4 Hv = hp[j];
        D4(az0, Hv, uz, 4 * j)  D4(az1, Hv, uz, 16 + 4 * j)
        D4(ar0, Hv, ur, 4 * j)  D4(ar1, Hv, ur, 16 + 4 * j)
      }
      // transpose-reduce across the quad: kg0<-r0, kg1<-r1, kg2<-z0, kg3<-z1
      // round 1 (xor1): R[kg0]=ar0[0]+ar0[1], R[kg1]=ar1[0]+ar1[1],
      //                 R[kg2]=ar0[2]+ar0[3], R[kg3]=ar1[2]+ar1[3]; Z likewise.
      const float sR = (kg & 1) ? ar1 : ar0;
      const float oR = (kg & 1) ? ar0 : ar1;
      const float sZ = (kg & 1) ? az1 : az0;
      const float oZ = (kg & 1) ? az0 : az1;
      const float Rp = sR + dpp1(oR);
      const float Zp = sZ + dpp1(oZ);
      // round 2 (xor2): kg0: R[0]+R[2]=full ar0; kg2: Z[2]+Z[0]=full az0; etc.
      const float s2 = (kg & 2) ? Zp : Rp;
      const float o2 = (kg & 2) ? Rp : Zp;
      const float G  = s2 + dpp2(o2);
      // single activation chain per lane (weights prescaled by log2e)
      const float gateB = __builtin_amdgcn_rcpf(1.0f + __builtin_amdgcn_exp2f(-(G + biasB)));
      if (kg < 2) ((_Float16*)s_rh16)[c0 + kg] = (_Float16)(gateB * hdk);
      const float zk = dpp2(gateB);   // kg0 <- z0 (from kg2), kg1 <- z1 (from kg3)
      __syncthreads();

      // ---- window C: candidate + update (+ next-step x-proj as filler) ----
      const float ghvk = s_ghv[tc * U_ + c0 + (kg & 1)];
      const uint4* rp = (const uint4*)(s_rh16 + 32 * kg);
      float ah0 = axh0, ah1 = axh1;
#pragma unroll
      for (int j = 0; j < 4; ++j) {
        const uint4 Rv = rp[j];
        D4(ah0, Rv, uh, 4 * j)  D4(ah1, Rv, uh, 16 + 4 * j)
      }
      if (tc < 31) {
        const uint4* xp = (const uint4*)(s_x16 + (tc + 1) * F_ + 16 * kg);
        float a0 = 0.f, a1 = 0.f, a2 = 0.f, a3 = 0.f, a4 = 0.f, a5 = 0.f;
#pragma unroll
        for (int q = 0; q < 2; ++q) {
          const uint4 Xv = xp[q];
          D4(a0, Xv, wz, 4 * q)  D4(a1, Xv, wz, 8 + 4 * q)
          D4(a2, Xv, wr, 4 * q)  D4(a3, Xv, wr, 8 + 4 * q)
          D4(a4, Xv, wh, 4 * q)  D4(a5, Xv, wh, 8 + 4 * q)
        }
        axz0 = a0; axz1 = a1; axr0 = a2; axr1 = a3; axh0 = a4; axh1 = a5;
      }
      // distributed reduce: kg0/kg2 get full ah0, kg1/kg3 get full ah1
      const float sH = (kg & 1) ? ah1 : ah0;
      const float oH = (kg & 1) ? ah0 : ah1;
      const float Hp = sH + dpp1(oH);
      const float Hf = Hp + dpp2(Hp);
      // tanh with folded 2*log2e prescale: tanh(x) = 1 - 2/(1+exp2(x'))
      const float hh = fmaf(-2.0f,
          __builtin_amdgcn_rcpf(1.0f + __builtin_amdgcn_exp2f(Hf + biasC)), 1.0f);
      const float hn = fmaf(zk, hh - hdk, hdk);
      hdk = ghvk * hn;
      if (kg < 2) {
        ((_Float16*)s_hd16)[c0 + kg] = (_Float16)hdk;   // unblock other waves ASAP
        s_hist[tc * U_ + c0 + kg] = hn;
      }
      __syncthreads();
    }

    // ======== flush chunk outputs (coalesced) ========
    {
      const float4* h4 = (const float4*)s_hist;
      float4* o4 = (float4*)(out + (size_t)(b * T_ + t0) * U_);
#pragma unroll
      for (int i = 0; i < 4; ++i) o4[tid + 256 * i] = h4[tid + 256 * i];
    }
  }
}

extern "C" void kernel_launch(void* const* d_in, const int* in_sizes, int n_in,
                              void* d_out, int out_size, void* d_ws, size_t ws_size,
                              hipStream_t stream) {
  const float* x   = (const float*)d_in[0];
  const float* m   = (const float*)d_in[1];
  const float* dt  = (const float*)d_in[2];
  const float* Wz  = (const float*)d_in[3];
  const float* Uz  = (const float*)d_in[4];
  const float* bz  = (const float*)d_in[5];
  const float* Wr  = (const float*)d_in[6];
  const float* Ur  = (const float*)d_in[7];
  const float* br  = (const float*)d_in[8];
  const float* Wh  = (const float*)d_in[9];
  const float* Uh  = (const float*)d_in[10];
  const float* bh  = (const float*)d_in[11];
  const float* gxd = (const float*)d_in[12];
  const float* ghd = (const float*)d_in[13];
  const float* mi  = (const float*)d_in[14];

  grud_kernel<<<dim3(B_), dim3(256), 0, stream>>>(
      x, m, dt, Wz, Uz, bz, Wr, Ur, br, Wh, Uh, bh, gxd, ghd, mi, (float*)d_out);
}